// Round 13
// baseline (182.356 us; speedup 1.0000x reference)
//
#include <hip/hip_runtime.h>
#include <hip/hip_bf16.h>

// B=32, C_IN=2048, C=1024, H=W=14, N_CLS=30
// pooled[b,c] = (1/14) * sum_h (conv_w @ mean_w f1)[b,c,h] * (mean_w f2)[b,c,h]
// out = pooled @ fc_w^T + fc_b
//
// *** MEASUREMENT ROUND: k1 launched 3x, k2 launched 2x (idempotent re-runs).
// *** Delta vs R10 total (133.9) = 2*k1_warm + k2 (+~6us node overhead).
// *** Kernels are bit-identical to R10.
//
// ws layout:
//   [0, 2MB)    f1mt  ushort(bf16) [512][2048]   rows n = b*16+h (h padded to 16, pad rows 0)
//   [2MB, 6MB)  cwb   ushort(bf16) [1024][2048]
//   [6MB, 8MB)  ym    float [32][16][1024]       (h=14,15 rows 0)
//   [8MB, 10MB) part  float [16][32][1024]       (one slice per k-chunk, plain stores)

typedef __attribute__((ext_vector_type(8))) short short8;
typedef __attribute__((ext_vector_type(4))) float f32x4;

static __device__ __forceinline__ unsigned short f2bf(float f) {
    union { float f; unsigned u; } v; v.f = f;
    return (unsigned short)((v.u + 0x7FFFu + ((v.u >> 16) & 1u)) >> 16);
}

#define LROW 197   // LDS row stride in floats: gcd(197,32)=1 -> conflict-free reduce

// ---------------- K1: coalesced LDS-staged reductions + cast -----------------
// blocks [0,1024):     jobA  f1 W-reduce -> bf16 f1mt   (block = one b x 64 i-rows)
// blocks [1024,1536):  jobB  f2 W-reduce -> f32 ym      (block = one b x 64 c-rows)
// blocks [1536,2560):  jobC  conv_w f32 -> bf16 cast    (8 elems/thread)
__global__ __launch_bounds__(256) void k1_prep(
    const float* __restrict__ f1, const float* __restrict__ f2,
    const float* __restrict__ cw,
    unsigned short* __restrict__ f1mt, unsigned short* __restrict__ cwb,
    float* __restrict__ ym)
{
    __shared__ float lds[64 * LROW];         // 50.4 KB: 64 rows x 197 floats
    const float inv14 = 1.0f / 14.0f;
    int blk = blockIdx.x;
    int tid = threadIdx.x;

    if (blk < 1024) {
        // jobA: b = blk>>5, rows i0..i0+63 (contiguous 49KB in f1)
        int b = blk >> 5, i0 = (blk & 31) * 64;
        const float4* src = (const float4*)(f1 + (size_t)(b * 2048 + i0) * 196);
        #pragma unroll
        for (int j = 0; j < 13; j++) {        // 3136 float4, fully coalesced reads
            unsigned idx = j * 256 + tid;
            if (idx < 3136) {
                unsigned row = idx / 49, col = idx - row * 49;
                *(float4*)&lds[row * LROW + col * 4] = src[idx];
            }
        }
        __syncthreads();
        int r  = tid & 63;                    // row within slab (lane -> coalesced write)
        int hb = tid >> 6;                    // wave id
        unsigned short* o = f1mt + (size_t)b * 16 * 2048 + i0 + r;
        #pragma unroll
        for (int it = 0; it < 4; it++) {
            int h = hb + it * 4;              // 0..15
            if (h < 14) {
                const float* p = &lds[r * LROW + h * 14];
                float s = 0.0f;
                #pragma unroll
                for (int q = 0; q < 14; q++) s += p[q];
                o[h * 2048] = f2bf(s * inv14);
            } else {
                o[h * 2048] = 0;              // pad rows 14,15
            }
        }
    } else if (blk < 1536) {
        // jobB: 16 blocks per b, 64 c-rows each
        int t = blk - 1024;
        int b = t >> 4, c0 = (t & 15) * 64;
        const float4* src = (const float4*)(f2 + (size_t)(b * 1024 + c0) * 196);
        #pragma unroll
        for (int j = 0; j < 13; j++) {
            unsigned idx = j * 256 + tid;
            if (idx < 3136) {
                unsigned row = idx / 49, col = idx - row * 49;
                *(float4*)&lds[row * LROW + col * 4] = src[idx];
            }
        }
        __syncthreads();
        int r  = tid & 63;
        int hb = tid >> 6;
        float* o = ym + (size_t)b * 16 * 1024 + c0 + r;
        #pragma unroll
        for (int it = 0; it < 4; it++) {
            int h = hb + it * 4;
            if (h < 14) {
                const float* p = &lds[r * LROW + h * 14];
                float s = 0.0f;
                #pragma unroll
                for (int q = 0; q < 14; q++) s += p[q];
                o[h * 1024] = s * inv14;
            } else {
                o[h * 1024] = 0.0f;
            }
        }
    } else {
        // jobC: cast conv_w (2M elems) to bf16, 8 per thread
        int t = (blk - 1536) * 256 + tid;
        const float4* p = (const float4*)(cw + (size_t)t * 8);
        float4 v0 = p[0], v1 = p[1];
        ushort4 a, b4;
        a.x = f2bf(v0.x); a.y = f2bf(v0.y); a.z = f2bf(v0.z); a.w = f2bf(v0.w);
        b4.x = f2bf(v1.x); b4.y = f2bf(v1.y); b4.z = f2bf(v1.z); b4.w = f2bf(v1.w);
        *(ushort4*)(cwb + (size_t)t * 8)     = a;
        *(ushort4*)(cwb + (size_t)t * 8 + 4) = b4;
    }
}

// ---------------- K2: bf16 MFMA GEMM fused with ym-mul + h-reduce ------------
// (bit-identical to R10; see R8 notes)
__global__ __launch_bounds__(256) void k2_gemm(
    const unsigned short* __restrict__ A,   // cwb  [1024][2048]
    const unsigned short* __restrict__ Bm,  // f1mt [512][2048]
    const float* __restrict__ ym,           // [512][1024]
    float* __restrict__ part)               // [16][32][1024]
{
    int tid = threadIdx.x;
    int w  = tid >> 6;
    int l  = tid & 63;
    int lg = l >> 4;          // lane k-group
    int lr = l & 15;          // lane row/col (== h in the C fragment)

    int bid = blockIdx.x;
    int sid = (bid & 7) * 128 + (bid >> 3);   // XCD-contiguous remap (bijective)
    int ct  = sid >> 6;          // 0..15  -> c0
    int rem = sid & 63;
    int nt  = rem >> 2;          // 0..15  -> n0
    int kq  = rem & 3;           // 0..3
    int c0 = ct * 64, n0 = nt * 32;
    int kc = kq * 4 + w;         // k-chunk id 0..15
    int kbase = kc * 128;

    const unsigned short* Ap = A  + (size_t)(c0 + lr) * 2048 + kbase + lg * 8;
    const unsigned short* Bp = Bm + (size_t)(n0 + lr) * 2048 + kbase + lg * 8;

    f32x4 acc[4][2];
    #pragma unroll
    for (int mf = 0; mf < 4; mf++)
        #pragma unroll
        for (int nf = 0; nf < 2; nf++)
            acc[mf][nf] = (f32x4){0.f, 0.f, 0.f, 0.f};

    #pragma unroll 1
    for (int half = 0; half < 2; half++) {   // not unrolled: caps frag pressure
        short8 af[4][2], bf[2][2];
        #pragma unroll
        for (int kk = 0; kk < 2; kk++) {
            int ko = half * 64 + kk * 32;
            #pragma unroll
            for (int mf = 0; mf < 4; mf++)
                af[mf][kk] = *(const short8*)(Ap + mf * 16 * 2048 + ko);
            #pragma unroll
            for (int nf = 0; nf < 2; nf++)
                bf[nf][kk] = *(const short8*)(Bp + nf * 16 * 2048 + ko);
        }
        #pragma unroll
        for (int kk = 0; kk < 2; kk++)
            #pragma unroll
            for (int mf = 0; mf < 4; mf++)
                #pragma unroll
                for (int nf = 0; nf < 2; nf++)
                    acc[mf][nf] = __builtin_amdgcn_mfma_f32_16x16x32_bf16(
                        af[mf][kk], bf[nf][kk], acc[mf][nf], 0, 0, 0);
    }

    // fused epilogue: part[kc][b][c] = (1/14) * sum_h xm_partial * ym
    const float inv14 = 1.0f / 14.0f;
    #pragma unroll
    for (int nf = 0; nf < 2; nf++) {
        int b = nt * 2 + nf;
        const float* yrow = ym + (size_t)(b * 16 + lr) * 1024 + c0 + lg * 4;  // h = lr
        #pragma unroll
        for (int mf = 0; mf < 4; mf++) {
            f32x4 yv = *(const f32x4*)(yrow + mf * 16);
            f32x4 pp = acc[mf][nf] * yv;
            #pragma unroll
            for (int st = 1; st <= 8; st <<= 1) {   // reduce over h (16 lanes)
                pp[0] += __shfl_xor(pp[0], st);
                pp[1] += __shfl_xor(pp[1], st);
                pp[2] += __shfl_xor(pp[2], st);
                pp[3] += __shfl_xor(pp[3], st);
            }
            if (lr == 0) {
                float* dst = part + (size_t)kc * 32768 + b * 1024 + c0 + mf * 16 + lg * 4;
                *(f32x4*)dst = pp * inv14;          // 4 lanes x 16B = 64B contiguous
            }
        }
    }
}

// ---------------- K3: reduce 16 k-partials + FC head (one block per b) -------
__global__ __launch_bounds__(1024) void k3_fc(
    const float* __restrict__ part, const float* __restrict__ fcw,
    const float* __restrict__ fcb, float* __restrict__ out)
{
    __shared__ float ps[1024];
    int b = blockIdx.x, tid = threadIdx.x;
    float s = 0.0f;
    #pragma unroll
    for (int k = 0; k < 16; k++)
        s += part[(size_t)k * 32768 + b * 1024 + tid];
    ps[tid] = s;
    __syncthreads();
    int w = tid >> 6, l = tid & 63;
    for (int n = w; n < 30; n += 16) {
        const float* wp = fcw + n * 1024;
        float t = 0.0f;
        #pragma unroll
        for (int it = 0; it < 16; it++)
            t += wp[l + it * 64] * ps[l + it * 64];   // scalar: 2-way LDS, free
        #pragma unroll
        for (int m = 32; m; m >>= 1) t += __shfl_xor(t, m);
        if (l == 0) out[b * 30 + n] = t + fcb[n];
    }
}

extern "C" void kernel_launch(void* const* d_in, const int* in_sizes, int n_in,
                              void* d_out, int out_size, void* d_ws, size_t ws_size,
                              hipStream_t stream) {
    const float* f1  = (const float*)d_in[0];   // [32,2048,14,14]
    const float* f2  = (const float*)d_in[1];   // [32,1024,14,14]
    const float* cw  = (const float*)d_in[2];   // [1024,2048]
    const float* fcw = (const float*)d_in[3];   // [30,1024]
    const float* fcb = (const float*)d_in[4];   // [30]
    float* out = (float*)d_out;                 // [32,30]

    unsigned short* f1mt = (unsigned short*)d_ws;
    unsigned short* cwb  = (unsigned short*)((char*)d_ws + (2u << 20));
    float* ym            = (float*)((char*)d_ws + (6u << 20));
    float* part          = (float*)((char*)d_ws + (8u << 20));

    // MEASUREMENT: k1 x3, k2 x2 (idempotent; delta = 2*k1_warm + k2)
    k1_prep<<<2560, 256, 0, stream>>>(f1, f2, cw, f1mt, cwb, ym);
    k1_prep<<<2560, 256, 0, stream>>>(f1, f2, cw, f1mt, cwb, ym);
    k1_prep<<<2560, 256, 0, stream>>>(f1, f2, cw, f1mt, cwb, ym);
    k2_gemm<<<1024, 256, 0, stream>>>(cwb, f1mt, ym, part);
    k2_gemm<<<1024, 256, 0, stream>>>(cwb, f1mt, ym, part);
    k3_fc<<<32, 1024, 0, stream>>>(part, fcw, fcb, out);
}

// Round 14
// 127.083 us; speedup vs baseline: 1.4349x; 1.4349x over previous
//
#include <hip/hip_runtime.h>
#include <hip/hip_bf16.h>

// B=32, C_IN=2048, C=1024, H=W=14, N_CLS=30
// pooled[b,c] = (1/14) * sum_h (conv_w @ mean_w f1)[b,c,h] * (mean_w f2)[b,c,h]
// out = pooled @ fc_w^T + fc_b
//
// R14: fragment-major ("pre-swizzled") operand layouts so ALL k2 loads are
// fully coalesced 1KB wave-loads (R13 ablation: k2 was L2-overfetch-bound,
// 4KB-strided 16B fragment loads = 4x sector waste).
//
// Layouts (slot = 16B = 8 bf16 elems or 4 f32):
//   afrag[c_blk 64][kk 64][lane 64]{8}: cw_bf16[c_blk*16+(l&15)][kk*32+(l>>4)*8+j]
//   bfrag[b 32][kk 64][lane 64]{8}:     f1m_bf16[b][kk*32+(l>>4)*8+j][h=l&15]
//   ymf  [b 32][cq 256][h 16]{4 f32}:   ym[b][h][cq*4+e]
//   part [kc 16][b 32][c 1024] f32
//
// ws: afrag 4MB @0, bfrag 2MB @4MB, ymf 2MB @6MB, part 2MB @8MB

typedef __attribute__((ext_vector_type(8))) short short8;
typedef __attribute__((ext_vector_type(4))) float f32x4;

static __device__ __forceinline__ unsigned short f2bf(float f) {
    union { float f; unsigned u; } v; v.f = f;
    return (unsigned short)((v.u + 0x7FFFu + ((v.u >> 16) & 1u)) >> 16);
}

#define JA 2048          // jobA blocks: 32 b x 64 kk (32 i-rows each)
#define JB (JA + 1024)   // jobB blocks: 32 b x 32 cc (32 c-rows each)
#define JC (JB + 1024)   // jobC blocks: 256K threads, 1 afrag slot each

// ---------------- K1: W-reductions + casts into fragment-major layouts ------
__global__ __launch_bounds__(256) void k1_prep(
    const float* __restrict__ f1, const float* __restrict__ f2,
    const float* __restrict__ cw,
    unsigned short* __restrict__ afrag, unsigned short* __restrict__ bfrag,
    float* __restrict__ ymf)
{
    __shared__ float lds[32 * 196];    // 24.5 KB staging slab (32 rows x 196)
    __shared__ float s_lds[32 * 16];   // row-sums tile [row][h]
    const float inv14 = 1.0f / 14.0f;
    int blk = blockIdx.x, tid = threadIdx.x;

    if (blk < JA) {
        // ---- jobA: f1 W-reduce -> bfrag. Block = (b, kk): rows i0..i0+31.
        int b = blk >> 6, kk = blk & 63;
        int i0 = kk * 32;
        const float4* src = (const float4*)(f1 + (size_t)(b * 2048 + i0) * 196);
        #pragma unroll
        for (int j = 0; j < 7; j++) {            // 1568 float4, linear copy
            int idx = j * 256 + tid;
            if (idx < 1568) *(float4*)&lds[idx * 4] = src[idx];
        }
        __syncthreads();
        #pragma unroll
        for (int it = 0; it < 2; it++) {         // (r = tid&31, h = tid>>5 + 8*it)
            int r = tid & 31, h = (tid >> 5) + it * 8;
            float s = 0.0f;
            if (h < 14) {
                const float* p = &lds[r * 196 + h * 14];
                #pragma unroll
                for (int q = 0; q < 14; q++) s += p[q];
                s *= inv14;
            }
            s_lds[r * 16 + h] = s;               // h=14,15 stay 0 (pad rows)
        }
        __syncthreads();
        if (tid < 64) {                          // 64 slots: lane = tid
            int lr = tid & 15, lg = tid >> 4;
            short8 pk;
            #pragma unroll
            for (int j = 0; j < 8; j++)
                pk[j] = (short)f2bf(s_lds[(lg * 8 + j) * 16 + lr]);
            *(short8*)(bfrag + (((size_t)b * 64 + kk) * 64 + tid) * 8) = pk;
        }
    } else if (blk < JB) {
        // ---- jobB: f2 W-reduce -> ymf. Block = (b, cc): c-rows c0..c0+31.
        int t = blk - JA;
        int b = t >> 5, cc = t & 31;
        int c0 = cc * 32;
        const float4* src = (const float4*)(f2 + (size_t)(b * 1024 + c0) * 196);
        #pragma unroll
        for (int j = 0; j < 7; j++) {
            int idx = j * 256 + tid;
            if (idx < 1568) *(float4*)&lds[idx * 4] = src[idx];
        }
        __syncthreads();
        #pragma unroll
        for (int it = 0; it < 2; it++) {
            int r = tid & 31, h = (tid >> 5) + it * 8;
            float s = 0.0f;
            if (h < 14) {
                const float* p = &lds[r * 196 + h * 14];
                #pragma unroll
                for (int q = 0; q < 14; q++) s += p[q];
                s *= inv14;
            }
            s_lds[r * 16 + h] = s;
        }
        __syncthreads();
        if (tid < 128) {                         // 128 slots: (cql 0..7, h 0..15)
            int cql = tid >> 4, h = tid & 15;
            f32x4 v;
            #pragma unroll
            for (int e = 0; e < 4; e++)
                v[e] = s_lds[(cql * 4 + e) * 16 + h];
            *(f32x4*)(ymf + (((size_t)b * 256 + cc * 8 + cql) * 16 + h) * 4) = v;
        }
    } else {
        // ---- jobC: cw f32 -> bf16 afrag, 1 slot/thread. Reads are fully
        // line-consumed: lanes' lg spans 4x8 k-offsets within each c-row.
        int t = (blk - JB) * 256 + tid;          // 0..262143
        int l = t & 63, kkg = (t >> 6) & 63, c_blk = t >> 12;
        int c  = c_blk * 16 + (l & 15);
        int i0 = kkg * 32 + (l >> 4) * 8;
        const float4* p = (const float4*)(cw + (size_t)c * 2048 + i0);
        float4 v0 = p[0], v1 = p[1];
        short8 pk;
        pk[0] = (short)f2bf(v0.x); pk[1] = (short)f2bf(v0.y);
        pk[2] = (short)f2bf(v0.z); pk[3] = (short)f2bf(v0.w);
        pk[4] = (short)f2bf(v1.x); pk[5] = (short)f2bf(v1.y);
        pk[6] = (short)f2bf(v1.z); pk[7] = (short)f2bf(v1.w);
        *(short8*)(afrag + ((size_t)(c_blk * 64 + kkg) * 64 + l) * 8) = pk;
    }
}

// ---------------- K2: bf16 MFMA GEMM fused with ym-mul + h-reduce ------------
// Same geometry as R10 (1024 blocks x 4 waves; wave = 64c x 32n x K128;
// split-K 16 -> part; XCD-bijective swizzle), but every fragment/ym load is
// now ONE contiguous 1KB wave-load from the fragment-major arrays.
__global__ __launch_bounds__(256) void k2_gemm(
    const unsigned short* __restrict__ afrag,
    const unsigned short* __restrict__ bfrag,
    const float* __restrict__ ymf,
    float* __restrict__ part)               // [16][32][1024]
{
    int tid = threadIdx.x;
    int w  = tid >> 6;
    int l  = tid & 63;
    int lg = l >> 4;
    int lr = l & 15;          // == h in the C fragment

    int bid = blockIdx.x;
    int sid = (bid & 7) * 128 + (bid >> 3);   // XCD-contiguous remap (bijective)
    int ct  = sid >> 6;          // 0..15
    int rem = sid & 63;
    int nt  = rem >> 2;          // 0..15
    int kq  = rem & 3;           // 0..3
    int c0 = ct * 64;
    int kc = kq * 4 + w;         // k-chunk id 0..15 (K128 each)

    f32x4 acc[4][2];
    #pragma unroll
    for (int mf = 0; mf < 4; mf++)
        #pragma unroll
        for (int nf = 0; nf < 2; nf++)
            acc[mf][nf] = (f32x4){0.f, 0.f, 0.f, 0.f};

    #pragma unroll 1
    for (int half = 0; half < 2; half++) {   // caps live-fragment pressure
        short8 af[4][2], bf[2][2];
        #pragma unroll
        for (int kkh = 0; kkh < 2; kkh++) {
            int kkg = kc * 4 + half * 2 + kkh;   // global k-chunk32 id
            #pragma unroll
            for (int mf = 0; mf < 4; mf++)
                af[mf][kkh] = *(const short8*)(
                    afrag + ((size_t)((ct * 4 + mf) * 64 + kkg) * 64 + l) * 8);
            #pragma unroll
            for (int nf = 0; nf < 2; nf++)
                bf[nf][kkh] = *(const short8*)(
                    bfrag + ((size_t)((nt * 2 + nf) * 64 + kkg) * 64 + l) * 8);
        }
        #pragma unroll
        for (int kkh = 0; kkh < 2; kkh++)
            #pragma unroll
            for (int mf = 0; mf < 4; mf++)
                #pragma unroll
                for (int nf = 0; nf < 2; nf++)
                    acc[mf][nf] = __builtin_amdgcn_mfma_f32_16x16x32_bf16(
                        af[mf][kkh], bf[nf][kkh], acc[mf][nf], 0, 0, 0);
    }

    // fused epilogue: part[kc][b][c] = (1/14) * sum_h xm_partial * ym
    const float inv14 = 1.0f / 14.0f;
    #pragma unroll
    for (int nf = 0; nf < 2; nf++) {
        int b = nt * 2 + nf;
        #pragma unroll
        for (int mf = 0; mf < 4; mf++) {
            // ym[b][h=lr][c = c0+mf*16+lg*4 .. +4] from ymf (coalesced 1KB)
            f32x4 yv = *(const f32x4*)(
                ymf + (((size_t)b * 256 + ct * 16 + mf * 4 + lg) * 16 + lr) * 4);
            f32x4 pp = acc[mf][nf] * yv;
            #pragma unroll
            for (int st = 1; st <= 8; st <<= 1) {   // reduce over h (16 lanes)
                pp[0] += __shfl_xor(pp[0], st);
                pp[1] += __shfl_xor(pp[1], st);
                pp[2] += __shfl_xor(pp[2], st);
                pp[3] += __shfl_xor(pp[3], st);
            }
            if (lr == 0) {
                float* dst = part + (size_t)kc * 32768 + b * 1024 + c0 + mf * 16 + lg * 4;
                *(f32x4*)dst = pp * inv14;          // 4 lanes = 64B contiguous
            }
        }
    }
}

// ---------------- K3: reduce 16 k-partials + FC head (one block per b) -------
__global__ __launch_bounds__(1024) void k3_fc(
    const float* __restrict__ part, const float* __restrict__ fcw,
    const float* __restrict__ fcb, float* __restrict__ out)
{
    __shared__ float ps[1024];
    int b = blockIdx.x, tid = threadIdx.x;
    float s = 0.0f;
    #pragma unroll
    for (int k = 0; k < 16; k++)
        s += part[(size_t)k * 32768 + b * 1024 + tid];
    ps[tid] = s;
    __syncthreads();
    int w = tid >> 6, l = tid & 63;
    for (int n = w; n < 30; n += 16) {
        const float* wp = fcw + n * 1024;
        float t = 0.0f;
        #pragma unroll
        for (int it = 0; it < 16; it++)
            t += wp[l + it * 64] * ps[l + it * 64];
        #pragma unroll
        for (int m = 32; m; m >>= 1) t += __shfl_xor(t, m);
        if (l == 0) out[b * 30 + n] = t + fcb[n];
    }
}

extern "C" void kernel_launch(void* const* d_in, const int* in_sizes, int n_in,
                              void* d_out, int out_size, void* d_ws, size_t ws_size,
                              hipStream_t stream) {
    const float* f1  = (const float*)d_in[0];   // [32,2048,14,14]
    const float* f2  = (const float*)d_in[1];   // [32,1024,14,14]
    const float* cw  = (const float*)d_in[2];   // [1024,2048]
    const float* fcw = (const float*)d_in[3];   // [30,1024]
    const float* fcb = (const float*)d_in[4];   // [30]
    float* out = (float*)d_out;                 // [32,30]

    unsigned short* afrag = (unsigned short*)d_ws;
    unsigned short* bfrag = (unsigned short*)((char*)d_ws + (4u << 20));
    float* ymf            = (float*)((char*)d_ws + (6u << 20));
    float* part           = (float*)((char*)d_ws + (8u << 20));

    k1_prep<<<4096, 256, 0, stream>>>(f1, f2, cw, afrag, bfrag, ymf);
    k2_gemm<<<1024, 256, 0, stream>>>(afrag, bfrag, ymf, part);
    k3_fc<<<32, 1024, 0, stream>>>(part, fcw, fcb, out);
}